// Round 1
// baseline (440.441 us; speedup 1.0000x reference)
//
#include <hip/hip_runtime.h>

#define NK 8
#define NV 8

// Input layout: inp[b][c][h][w], C = NK + NK*NV + NV = 80, HW = 512*512 contiguous per channel.
// Each thread handles 4 consecutive w positions (one float4 per channel access).
__global__ __launch_bounds__(256) void dpa_kernel(const float* __restrict__ inp,
                                                  float* __restrict__ out) {
    constexpr int HW = 512 * 512;          // 262144
    constexpr int C = NK + NK * NV + NV;   // 80
    const float scale = 0.35355339059327373f; // 1/sqrt(8)

    int idx = blockIdx.x * blockDim.x + threadIdx.x; // one float4 (4 pixels) per thread
    int b  = idx >> 16;          // HW/4 = 65536 float4's per batch-plane
    int s4 = idx & 65535;
    const float* pin = inp + (size_t)b * C * HW + (size_t)s4 * 4;

    // ---- load q (8 channels) ----
    float4 q[NK];
#pragma unroll
    for (int i = 0; i < NK; ++i)
        q[i] = *reinterpret_cast<const float4*>(pin + (size_t)i * HW);

    // ---- qk[v] = sum_k q[k] * K[k][v] ----
    float4 qk[NV];
#pragma unroll
    for (int v = 0; v < NV; ++v) qk[v] = make_float4(0.f, 0.f, 0.f, 0.f);

#pragma unroll
    for (int kk = 0; kk < NK; ++kk) {
#pragma unroll
        for (int v = 0; v < NV; ++v) {
            float4 kv = *reinterpret_cast<const float4*>(
                pin + (size_t)(NK + kk * NV + v) * HW);
            qk[v].x = fmaf(q[kk].x, kv.x, qk[v].x);
            qk[v].y = fmaf(q[kk].y, kv.y, qk[v].y);
            qk[v].z = fmaf(q[kk].z, kv.z, qk[v].z);
            qk[v].w = fmaf(q[kk].w, kv.w, qk[v].w);
        }
    }

    // ---- softmax over v (per float4 component), then multiply by v-channels ----
    float4 attn[NV];
#pragma unroll
    for (int c = 0; c < 4; ++c) {
        float t[NV];
#pragma unroll
        for (int v = 0; v < NV; ++v)
            t[v] = reinterpret_cast<const float*>(&qk[v])[c] * scale;
        float m = t[0];
#pragma unroll
        for (int v = 1; v < NV; ++v) m = fmaxf(m, t[v]);
        float e[NV], sum = 0.f;
#pragma unroll
        for (int v = 0; v < NV; ++v) { e[v] = __expf(t[v] - m); sum += e[v]; }
        float inv = 1.0f / sum;
#pragma unroll
        for (int v = 0; v < NV; ++v)
            reinterpret_cast<float*>(&attn[v])[c] = e[v] * inv;
    }

    // ---- out[b][v][h][w] = attn[v] * vchan[v] ----
    float* pout = out + (size_t)b * NV * HW + (size_t)s4 * 4;
#pragma unroll
    for (int v = 0; v < NV; ++v) {
        float4 vv = *reinterpret_cast<const float4*>(
            pin + (size_t)(NK + NK * NV + v) * HW);
        float4 r;
        r.x = attn[v].x * vv.x;
        r.y = attn[v].y * vv.y;
        r.z = attn[v].z * vv.z;
        r.w = attn[v].w * vv.w;
        *reinterpret_cast<float4*>(pout + (size_t)v * HW) = r;
    }
}

extern "C" void kernel_launch(void* const* d_in, const int* in_sizes, int n_in,
                              void* d_out, int out_size, void* d_ws, size_t ws_size,
                              hipStream_t stream) {
    const float* inp = (const float*)d_in[0];
    float* out = (float*)d_out;

    constexpr int HW = 512 * 512;
    constexpr int C = NK + NK * NV + NV; // 80
    int B = in_sizes[0] / (C * HW);      // 4

    int nThreads = B * (HW / 4);         // one float4 per thread
    dim3 block(256);
    dim3 grid(nThreads / 256);
    dpa_kernel<<<grid, block, 0, stream>>>(inp, out);
}